// Round 4
// baseline (770.049 us; speedup 1.0000x reference)
//
#include <hip/hip_runtime.h>

// CTC loss forward, B=256, T=1024, C=256, L=128, S=257, blank=255.
// Pass 1 (memory-bound prep): per row t of batch b, with q = p + eps,
//   D = sum(p) + C*eps, mx = max(q):
//   khat[row]  = log2(mx) - log2(D)        (per-step invariant factor)
//   cbh[row]   = bf16(q[blank]/mx)         (blank weight, <= 1)
//   cpack[row][lane] = bf16(q[lab(2l)]/mx) : bf16(q[lab(2l+1)]/mx)
// Pass 2 (latency-bound DP): one wave per b. Lane i owns states 4i..4i+3
// (lane 63 also state 256). All weights <= 1 -> bounded growth; periodic
// measured power-of-2 rescale (target 2^50, 16-step window, pipelined
// 6-stage shuffle max). Neighbor state via DPP wave_shr:1.
// loss = -ln2 * ( log2(a[S-1]+a[S-2]) + Rtot + sum_t khat )

#define B_DIM 256
#define T_DIM 1024
#define C_DIM 256
#define L_DIM 128
#define EPSF  (1e-7f)
#define CEPSF (256.0f * 1e-7f)
#define LN2F  (0.6931471805599453f)

__device__ __forceinline__ unsigned bf16_rne(float x) {
    unsigned u = __float_as_uint(x);
    return (u + 0x7FFFu + ((u >> 16) & 1u)) >> 16;
}

// ---------------- pass 1: row prep ----------------
__global__ __launch_bounds__(256) void prep_kernel(const int* __restrict__ yt,
                                                   const float* __restrict__ yp,
                                                   float* __restrict__ khat,
                                                   unsigned short* __restrict__ cbh,
                                                   unsigned* __restrict__ cpack) {
    __shared__ float rbuf[4][C_DIM];
    const int w    = threadIdx.x >> 6;
    const int lane = threadIdx.x & 63;
    const int row  = (blockIdx.x << 2) + w;        // 0 .. B*T-1
    const int b    = row >> 10;

    const float4* rp = (const float4*)(yp + (size_t)row * C_DIM);
    float4 v = rp[lane];
    *(float4*)&rbuf[w][lane << 2] = v;

    float s  = v.x + v.y + v.z + v.w;
    float mx = fmaxf(fmaxf(v.x, v.y), fmaxf(v.z, v.w));
    #pragma unroll
    for (int d = 1; d < 64; d <<= 1) {
        s  += __shfl_xor(s, d, 64);
        mx  = fmaxf(mx, __shfl_xor(mx, d, 64));
    }
    mx += EPSF;                                   // max of q = max(p) + eps
    float qB = __shfl(v.w, 63, 64) + EPSF;
    float inv = 1.0f / mx;

    const int2 l12 = ((const int2*)(yt + b * L_DIM))[lane];
    float q1 = rbuf[w][l12.x] + EPSF;
    float q3 = rbuf[w][l12.y] + EPSF;
    cpack[(size_t)row * 64 + lane] = (bf16_rne(q1 * inv) << 16) | bf16_rne(q3 * inv);

    if (lane == 0) {
        khat[row] = log2f(mx) - log2f(s + CEPSF);
        cbh[row]  = (unsigned short)bf16_rne(qB * inv);
    }
}

// ---------------- pass 2: DP ----------------
__global__ __launch_bounds__(64, 1) void ctc_dp_kernel(const int* __restrict__ yt,
                                                       const float* __restrict__ khat,
                                                       const unsigned short* __restrict__ cbh,
                                                       const unsigned* __restrict__ cpack,
                                                       float* __restrict__ out)
{
    const int b = blockIdx.x, lane = threadIdx.x;
    const unsigned* cp  = cpack + (size_t)b * (T_DIM * 64);
    const unsigned* cbp = (const unsigned*)(cbh + b * T_DIM);   // 512 row-pairs
    const bool l0 = (lane == 0);

    // K_b = sum over rows of khat
    float K = 0.0f;
    #pragma unroll
    for (int j = 0; j < 16; ++j) K += khat[b * T_DIM + (j << 6) + lane];
    #pragma unroll
    for (int d = 1; d < 64; d <<= 1) K += __shfl_xor(K, d, 64);

    // labels: lane i owns states 4i..4i+3; odd states have labels 2i, 2i+1
    const int2 l12 = ((const int2*)(yt + b * L_DIM))[lane];
    const int labm = __shfl_up(l12.y, 1, 64);   // lab[2*lane-1] (junk on lane 0)
    const float sk1 = (l0 || (l12.x != labm)) ? 1.0f : 0.0f;
    const float sk3 = (l12.y != l12.x) ? 1.0f : 0.0f;

    // register rings: cpack slot r&31 holds row r; cbring slot j&15 holds pair j
    unsigned ring[32];
    #pragma unroll
    for (int u = 0; u < 32; ++u) ring[u] = cp[(u << 6) + lane];
    unsigned cbring[16];
    #pragma unroll
    for (int u = 0; u < 16; ++u) cbring[u] = cbp[u];

    // init (t = 0): alpha'[0] = cB(0), alpha'[1] = c1(0) on lane 0
    float a0, a1, a2 = 0.0f, a3 = 0.0f, a4 = 0.0f;
    {
        float cB0 = __uint_as_float(cbring[0] << 16);
        float c10 = __uint_as_float(ring[0] & 0xFFFF0000u);
        a0 = l0 ? cB0 : 0.0f;
        a1 = l0 ? c10 : 0.0f;
    }
    float px3 = 0.0f;                 // x3 of previous step
    float Rtot = 0.0f, m = 1.0f, wv = 1.0f, s1f = 1.0f, s2f = 1.0f;

#define STEPX(T_, APPLY_, DOPF_) do {                                       \
        unsigned u_  = ring[(T_) & 31];                                     \
        unsigned ub_ = cbring[((T_) >> 1) & 15];                            \
        float c1_ = __uint_as_float(u_ & 0xFFFF0000u);                      \
        float c3_ = __uint_as_float(u_ << 16);                              \
        float cB_ = __uint_as_float(((T_) & 1) ? (ub_ & 0xFFFF0000u)        \
                                               : (ub_ << 16));              \
        float prev_ = __int_as_float(__builtin_amdgcn_update_dpp(           \
            0, __float_as_int(px3), 0x138, 0xF, 0xF, true));                \
        if (APPLY_) { prev_ *= s1f; prev_ *= s2f;                           \
            a0 *= s1f; a1 *= s1f; a2 *= s1f; a3 *= s1f; a4 *= s1f;          \
            a0 *= s2f; a1 *= s2f; a2 *= s2f; a3 *= s2f; a4 *= s2f; }        \
        float x0 = (a0 + prev_) * cB_;                                      \
        float x1 = fmaf(sk1, prev_, a0 + a1) * c1_;                         \
        float x2 = (a1 + a2) * cB_;                                         \
        float x3 = fmaf(sk3, a1, a2 + a3) * c3_;                            \
        float x4 = (a3 + a4) * cB_;                                         \
        a0 = x0; a1 = x1; a2 = x2; a3 = x3; a4 = x4; px3 = x3;              \
        if (DOPF_) ring[((T_) - 1) & 31] = cp[(((T_) + 31) << 6) + lane];   \
        if (((T_) & 1) && (T_) <= 991)                                      \
            cbring[((T_) >> 1) & 15] = cbp[((T_) >> 1) + 16];               \
    } while (0)

#define STAGE(KS_) do {                                                     \
        if ((KS_) == 0)  { m = fmaxf(fmaxf(a0, a1),                         \
                                     fmaxf(fmaxf(a2, a3), a4));             \
                           wv = __shfl_xor(m, 1, 64); }                     \
        if ((KS_) == 2)  { m = fmaxf(m, wv); wv = __shfl_xor(m, 2, 64); }   \
        if ((KS_) == 4)  { m = fmaxf(m, wv); wv = __shfl_xor(m, 4, 64); }   \
        if ((KS_) == 6)  { m = fmaxf(m, wv); wv = __shfl_xor(m, 8, 64); }   \
        if ((KS_) == 8)  { m = fmaxf(m, wv); wv = __shfl_xor(m, 16, 64); }  \
        if ((KS_) == 10) { m = fmaxf(m, wv); wv = __shfl_xor(m, 32, 64); }  \
        if ((KS_) == 12) { m = fmaxf(m, wv);                                \
                           int E  = (__float_as_int(m) >> 23) - 127;        \
                           int sh = 50 - E;                                 \
                           Rtot -= (float)sh;                               \
                           int sh1 = sh >> 1, sh2 = sh - sh1;               \
                           s1f = __int_as_float((sh1 + 127) << 23);         \
                           s2f = __int_as_float((sh2 + 127) << 23); }       \
    } while (0)

    // peel: t = 1..31 (first rescale measured at t=16, applied at t=29)
    #pragma unroll
    for (int k = 1; k < 32; ++k) {
        if (k >= 16) STAGE(k - 16);
        STEPX(k, (k == 29), 1);
    }

    // main: t = 32 .. 1023
    for (int t0 = 32; t0 < T_DIM; t0 += 32) {
        #pragma unroll
        for (int k = 0; k < 32; ++k) {
            STAGE(k & 15);
            STEPX(t0 + k, ((k & 15) == 13), ((t0 + k) <= T_DIM - 32));
        }
    }

    if (lane == 63) {
        float v = a3 + a4;    // states 255 (a3) and 256 (a4)
        out[b] = -(log2f(v) + Rtot + K) * LN2F;
    }
#undef STEPX
#undef STAGE
}

extern "C" void kernel_launch(void* const* d_in, const int* in_sizes, int n_in,
                              void* d_out, int out_size, void* d_ws, size_t ws_size,
                              hipStream_t stream) {
    const int*   yt = (const int*)d_in[0];     // y_true [256,128] int32
    const float* yp = (const float*)d_in[1];   // y_pred [256,1024,256] f32
    float* out = (float*)d_out;                // [256,1] f32
    float*          khat  = (float*)d_ws;                             // 1 MB
    unsigned short* cbh   = (unsigned short*)((char*)d_ws + (1u << 20));   // 0.5 MB
    unsigned*       cpack = (unsigned*)((char*)d_ws + (2u << 20));    // 64 MB
    (void)in_sizes; (void)n_in; (void)out_size; (void)ws_size;
    prep_kernel<<<dim3((B_DIM * T_DIM) / 4), dim3(256), 0, stream>>>(yt, yp, khat, cbh, cpack);
    ctc_dp_kernel<<<dim3(B_DIM), dim3(64), 0, stream>>>(yt, khat, cbh, cpack, out);
}